// Round 6
// baseline (143.382 us; speedup 1.0000x reference)
//
#include <hip/hip_runtime.h>

#define N_NODES 50000
#define N_EDGES 800000
#define D 64

#define NPB 200                      // nodes per bucket (bin key)
#define NB  250                      // buckets (NPB*NB == N_NODES)
#define CAP 4096                     // record capacity per bucket (mean 3200, 15.8 sigma)
#define BT  512                      // threads for bin (8 waves)
#define EPT 8                        // edges per thread in bin (R16 best)
#define CHUNK_E (BT * EPT)           // 4096 edges per block
#define NCHUNKS ((N_EDGES + CHUNK_E - 1) / CHUNK_E)   // 196
#define CONVB 256                    // h->bf16 conversion blocks appended to bin grid

#define CGT 512                      // csr_gather threads (8 waves)
#define NPH 100                      // nodes per half-bucket (csr_gather block)
#define HCAP 2048                    // stage capacity per half (mean 1600, 11 sigma)
#define NTILE ((NPH + 15) / 16)      // 7 MFMA row-tiles per half (last 4 rows masked)

typedef unsigned short ushort_t;
typedef unsigned int   uint_t;
typedef __attribute__((ext_vector_type(8))) short   short8;
typedef __attribute__((ext_vector_type(4))) float   float4v;

// bf16 helpers (RNE down-convert; up-convert is exact)
__device__ __forceinline__ ushort_t f2b(float f) {
    uint_t u = __float_as_uint(f);
    return (ushort_t)((u + 0x7FFFu + ((u >> 16) & 1u)) >> 16);
}
__device__ __forceinline__ float b2f(ushort_t b) {
    return __uint_as_float((uint_t)b << 16);
}
// fp32 bits -> bf16 bits (RNE), kept in the HIGH 16 bits of a uint
__device__ __forceinline__ uint_t rne_hi16(uint_t u) {
    return (u + 0x7FFFu + ((u >> 16) & 1u)) & 0xFFFF0000u;
}
__device__ __forceinline__ float lane_bcast(float v, int l) {
    return __int_as_float(__builtin_amdgcn_readlane(__float_as_int(v), l));
}

// ---------------------------------------------------------------------------
// ws layout (16B-aligned sections):
//   bedges : int2[NB*CAP]     (8.19 MB) bucket-grouped packed records (bin out)
//   h_bf16 : ushort[N*D]      (6.4 MB)
//   cursor : int[NB]          (memset 0; bin rebases to b*CAP + old)
// Binned record: .x=(src<<8)|local_dst, .y=bits(w).
//
// Ground-truth ledger (R17/R5 measured): total 142.2 = fill 46.5 (harness
// poison fill of 268 MB ws, irreducible) + bin ~42 + csr_gather 51.5 +
// memset/gaps ~2.
//  - R5: fused csr+gather = 51.5 ~= old csr 4 + gather 47.4. Fusion killed
//    pedges round-trip but dropped occupancy 54->34% (250 blocks on 256
//    CUs = max 1 block/CU = 16 of 32 wave slots).
//  - R18 (this): half-bucket split -> 500 blocks x 512 thr, 24 KB LDS ->
//    4 blocks/CU (32 waves, 100%). bin byte-identical. Predict csr_gather
//    ~40-44; if <= bin, bin finally enters top-5 (measured, not inferred).
//  - Observed wall worth remembering: every 800k-edge random-access pass
//    measures 42-50 us (hist 45, scatter 50, gather 47, bin 42).
// ---------------------------------------------------------------------------

// ---------------- K1: bin edges by bucket (blocks < NCHUNKS) + h->bf16 (rest) ----
__global__ __launch_bounds__(BT) void bin_h2b_kernel(
    const int* __restrict__ src, const int* __restrict__ dst,
    const float* __restrict__ w, int* __restrict__ cursor,
    int2* __restrict__ bedges,
    const float* __restrict__ h, ushort_t* __restrict__ hb)
{
    if (blockIdx.x >= NCHUNKS) {
        const int nb = gridDim.x - NCHUNKS;
        for (int i = (blockIdx.x - NCHUNKS) * BT + threadIdx.x;
             i < N_NODES * D / 4; i += nb * BT) {
            const float4 v = ((const float4*)h)[i];
            ushort4 o;
            o.x = f2b(v.x); o.y = f2b(v.y); o.z = f2b(v.z); o.w = f2b(v.w);
            ((ushort4*)hb)[i] = o;
        }
        return;
    }

    __shared__ int lh[NB];
    __shared__ int loff[NB];
    __shared__ int lcur[NB];
    __shared__ int gpos[NB];
    __shared__ int part[256];
    __shared__ int2 stage[CHUNK_E];
    __shared__ unsigned char sbk[CHUNK_E];

    const int t = threadIdx.x;
    for (int i = t; i < NB; i += BT) lh[i] = 0;
    __syncthreads();

    const int base = blockIdx.x * CHUNK_E;
    int   my_b[EPT];
    int   my_p[EPT];
    float my_w[EPT];
#pragma unroll
    for (int k = 0; k < EPT; ++k) {
        const int e = base + k * BT + t;
        if (e < N_EDGES) {
            const int d = dst[e];
            const int b = (unsigned)d / NPB;
            my_b[k] = b;
            my_p[k] = (src[e] << 8) | (d - b * NPB);
            my_w[k] = w[e];
            atomicAdd(&lh[b], 1);
        } else {
            my_b[k] = -1;
        }
    }
    __syncthreads();

    const int v = (t < NB) ? lh[t] : 0;
    if (t < 256) part[t] = v;
    __syncthreads();
    for (int off = 1; off < 256; off <<= 1) {
        int p = 0;
        if (t < 256 && t >= off) p = part[t - off];
        __syncthreads();
        if (t < 256) part[t] += p;
        __syncthreads();
    }
    if (t < NB) { loff[t] = part[t] - v; lcur[t] = part[t] - v; }
    __syncthreads();

#pragma unroll
    for (int k = 0; k < EPT; ++k) {
        if (my_b[k] >= 0) {
            const int p = atomicAdd(&lcur[my_b[k]], 1);
            stage[p] = make_int2(my_p[k], __float_as_int(my_w[k]));
            sbk[p] = (unsigned char)my_b[k];
        }
    }
    __syncthreads();

    if (t < NB && lh[t] > 0)
        gpos[t] = t * CAP + atomicAdd(&cursor[t], lh[t]);
    __syncthreads();

    const int tot = min(N_EDGES - base, CHUNK_E);
    for (int s = t; s < tot; s += BT) {
        const int b = sbk[s];
        bedges[gpos[b] + (s - loff[b])] = stage[s];
    }
}

// ---------------- K2: fused half-bucket sort + gather + MFMA linear ----------
// Block = (bucket, half). Reads the bucket's full record list, keeps its
// 100-node half. Phase A: node-exact counting sort into LDS. Phase B: 8
// waves x 12.5 nodes register-accumulate. Phase C: 7x4 MFMA tile tasks.
__global__ __launch_bounds__(CGT) void csr_gather_kernel(
    const int* __restrict__ cursor, const int2* __restrict__ bedges,
    const ushort_t* __restrict__ hb,
    const float* __restrict__ Ws, const float* __restrict__ bs,
    const float* __restrict__ Wn, const float* __restrict__ bn,
    float* __restrict__ out)
{
    __shared__ int      offs[NPH + 1];
    __shared__ int      lcur[NPH];
    __shared__ int      part[128];
    __shared__ __align__(16) uint_t   stage[HCAP];             // 8 KB
    __shared__ __align__(16) ushort_t nstage[NTILE * 16 * D];  // 14 KB

    const int blk = blockIdx.x;
    const int b   = blk >> 1;           // bucket 0..249
    const int lo  = (blk & 1) * NPH;    // local-node base of my half
    const int t   = threadIdx.x;
    const int gb  = b * CAP;
    const int cnt = min(cursor[b], CAP);

    // ---- phase A: histogram of my half ----
    if (t < NPH) lcur[t] = 0;
    __syncthreads();
    for (int e = t; e < cnt; e += CGT) {
        const unsigned ll = (unsigned)((bedges[gb + e].x & 255) - lo);
        if (ll < NPH) atomicAdd(&lcur[ll], 1);
    }
    __syncthreads();

    // exclusive scan of NPH counts (128-thread Hillis-Steele)
    const int v = (t < NPH) ? lcur[t] : 0;
    if (t < 128) part[t] = v;
    __syncthreads();
    for (int off = 1; off < 128; off <<= 1) {
        int p = 0;
        if (t < 128 && t >= off) p = part[t - off];
        __syncthreads();
        if (t < 128) part[t] += p;
        __syncthreads();
    }
    if (t < NPH) {
        const int ex = part[t] - v;
        offs[t] = ex;
        lcur[t] = ex;
    }
    if (t == 0) offs[NPH] = part[127];  // total records in my half
    // zero nstage pad rows (100..111) so tile 7's A-neigh reads are defined
    for (int i = t; i < (NTILE * 16 - NPH) * D; i += CGT) nstage[NPH * D + i] = 0;
    __syncthreads();

    // positioned scatter of my half's records into LDS stage
    for (int e = t; e < cnt; e += CGT) {
        const int2 r = bedges[gb + e];
        const unsigned ll = (unsigned)((r.x & 255) - lo);
        if (ll < NPH) {
            const int p = atomicAdd(&lcur[ll], 1);
            stage[min(p, HCAP - 1)] = (uint_t)(r.x >> 8) | rne_hi16((uint_t)r.y);
        }
    }
    __syncthreads();

    // ---- phase B: per-node gather-accumulate from LDS records ----
    const int wave = t >> 6;
    const int lane = t & 63;
    const int nbeg = wave * 12 + min(wave, 4);      // waves 0-3: 13 nodes, 4-7: 12
    const int ncnt = 12 + (wave < 4 ? 1 : 0);
    for (int ni = 0; ni < ncnt; ++ni) {
        const int n   = nbeg + ni;
        const int beg = min(offs[n], HCAP);
        const int end = min(offs[n + 1], HCAP);
        float acc = 0.f;
        int e = beg;
        for (; e + 8 <= end; e += 8) {
            uint_t r[8];
            float  vv[8];
#pragma unroll
            for (int k = 0; k < 8; ++k) r[k] = stage[e + k];
#pragma unroll
            for (int k = 0; k < 8; ++k)
                vv[k] = b2f(hb[(size_t)(r[k] & 0xFFFFu) * D + lane]);
#pragma unroll
            for (int k = 0; k < 8; ++k)
                acc = fmaf(__uint_as_float(r[k] & 0xFFFF0000u), vv[k], acc);
        }
        for (; e < end; ++e) {
            const uint_t r = stage[e];
            acc = fmaf(__uint_as_float(r & 0xFFFF0000u),
                       b2f(hb[(size_t)(r & 0xFFFFu) * D + lane]), acc);
        }
        nstage[n * D + lane] = f2b(acc);
    }
    __syncthreads();

    // ---- phase C: MFMA linear, NTILE*4 = 28 tile tasks over 8 waves ----
    const int node0  = b * NPB + lo;    // first output node of my half
    const int row16  = lane & 15;
    const int quad   = lane >> 4;
    for (int task = wave; task < NTILE * 4; task += 8) {
        const int m  = task >> 2;       // row tile 0..6
        const int nt = task & 3;        // col tile 0..3
        const int arow = m * 16 + row16;

        // A-self rows: node0+arow may overrun by <=11 rows for m==6; reads
        // land in later ws sections (in-bounds of allocation) and outputs
        // are store-masked below.
        const size_t abase = (size_t)(node0 + arow) * D + quad * 8;
        const short8 ah0 = *(const short8*)(hb + abase);
        const short8 ah1 = *(const short8*)(hb + abase + 32);
        const ushort_t* sp = nstage + arow * D + quad * 8;
        const short8 an0 = *(const short8*)sp;
        const short8 an1 = *(const short8*)(sp + 32);

        const int col = nt * 16 + row16;
        const float* wsr = Ws + (size_t)col * D + quad * 8;
        const float* wnr = Wn + (size_t)col * D + quad * 8;
        short8 bw[4];   // ws_k0, ws_k1, wn_k0, wn_k1
#pragma unroll
        for (int f = 0; f < 4; ++f) {
            const float* p = (f < 2 ? wsr : wnr) + (f & 1) * 32;
            const float4 w0 = *(const float4*)p;
            const float4 w1 = *(const float4*)(p + 4);
            short8 bwv;
            bwv[0] = (short)f2b(w0.x); bwv[1] = (short)f2b(w0.y);
            bwv[2] = (short)f2b(w0.z); bwv[3] = (short)f2b(w0.w);
            bwv[4] = (short)f2b(w1.x); bwv[5] = (short)f2b(w1.y);
            bwv[6] = (short)f2b(w1.z); bwv[7] = (short)f2b(w1.w);
            bw[f] = bwv;
        }
        float4v acc = {0.f, 0.f, 0.f, 0.f};
        acc = __builtin_amdgcn_mfma_f32_16x16x32_bf16(ah0, bw[0], acc, 0, 0, 0);
        acc = __builtin_amdgcn_mfma_f32_16x16x32_bf16(ah1, bw[1], acc, 0, 0, 0);
        acc = __builtin_amdgcn_mfma_f32_16x16x32_bf16(an0, bw[2], acc, 0, 0, 0);
        acc = __builtin_amdgcn_mfma_f32_16x16x32_bf16(an1, bw[3], acc, 0, 0, 0);

        const float bias = bs[col] + bn[col];
#pragma unroll
        for (int r = 0; r < 4; ++r) {
            const int mr = m * 16 + quad * 4 + r;   // row within my half
            if (mr < NPH)
                out[(size_t)(node0 + mr) * D + col] = fmaxf(acc[r] + bias, 0.f);
        }
    }
}

// ---------------- fallback path (ws too small): fp32 atomic scatter ----------------
__global__ __launch_bounds__(256) void sage_scatter(
    const float* __restrict__ h,
    const int* __restrict__ edge_src,
    const int* __restrict__ edge_dst,
    const float* __restrict__ edge_w,
    float* __restrict__ neigh)
{
    const long long tid = (long long)blockIdx.x * blockDim.x + threadIdx.x;
    const int e = (int)(tid >> 6);
    const int d = (int)(tid & 63);
    if (e >= N_EDGES) return;
    atomicAdd(&neigh[(long long)edge_dst[e] * D + d],
              edge_w[e] * h[(long long)edge_src[e] * D + d]);
}

__global__ __launch_bounds__(256, 2) void linear_f32_kernel(
    const float* __restrict__ h, const float* __restrict__ neigh,
    const float* __restrict__ Ws, const float* __restrict__ bs,
    const float* __restrict__ Wn, const float* __restrict__ bn,
    float* __restrict__ out)
{
    const int lane   = threadIdx.x & 63;
    const int gwave  = (blockIdx.x * blockDim.x + threadIdx.x) >> 6;
    const int nwaves = (gridDim.x * blockDim.x) >> 6;

    float Wsr[D], Wnr[D];
#pragma unroll
    for (int k = 0; k < D; k += 4) {
        const float4 a = *(const float4*)&Ws[(size_t)lane * D + k];
        const float4 b = *(const float4*)&Wn[(size_t)lane * D + k];
        Wsr[k] = a.x; Wsr[k+1] = a.y; Wsr[k+2] = a.z; Wsr[k+3] = a.w;
        Wnr[k] = b.x; Wnr[k+1] = b.y; Wnr[k+2] = b.z; Wnr[k+3] = b.w;
    }
    const float bias = bs[lane] + bn[lane];

    for (int n = gwave; n < N_NODES; n += nwaves) {
        const float hv = h[(size_t)n * D + lane];
        const float nv = neigh[(size_t)n * D + lane];
        float o = bias;
#pragma unroll
        for (int k = 0; k < D; ++k) {
            o = fmaf(lane_bcast(hv, k), Wsr[k], o);
            o = fmaf(lane_bcast(nv, k), Wnr[k], o);
        }
        out[(size_t)n * D + lane] = fmaxf(o, 0.f);
    }
}

extern "C" void kernel_launch(void* const* d_in, const int* in_sizes, int n_in,
                              void* d_out, int out_size, void* d_ws, size_t ws_size,
                              hipStream_t stream)
{
    const float* h        = (const float*)d_in[0];
    const int*   edge_src = (const int*)d_in[1];
    const int*   edge_dst = (const int*)d_in[2];
    const float* edge_w   = (const float*)d_in[3];
    const float* W_self   = (const float*)d_in[4];
    const float* b_self   = (const float*)d_in[5];
    const float* W_neigh  = (const float*)d_in[6];
    const float* b_neigh  = (const float*)d_in[7];
    float*       out      = (float*)d_out;

    // ws layout
    int2*     bedges = (int2*)d_ws;                               // NB*CAP int2
    ushort_t* hb     = (ushort_t*)(bedges + (size_t)NB * CAP);    // N*D ushort
    int*      cursor = (int*)(hb + (size_t)N_NODES * D);          // NB
    const size_t needed = (size_t)NB * CAP * 8 + (size_t)N_NODES * D * 2 + NB * 4;

    if (ws_size >= needed) {
        hipMemsetAsync(cursor, 0, NB * sizeof(int), stream);
        bin_h2b_kernel<<<NCHUNKS + CONVB, BT, 0, stream>>>(
            edge_src, edge_dst, edge_w, cursor, bedges, h, hb);
        csr_gather_kernel<<<NB * 2, CGT, 0, stream>>>(
            cursor, bedges, hb, W_self, b_self, W_neigh, b_neigh, out);
    } else {
        float* neigh_fb = (float*)d_ws;
        hipMemsetAsync(neigh_fb, 0, (size_t)N_NODES * D * sizeof(float), stream);
        const long long total = (long long)N_EDGES * 64;
        sage_scatter<<<(int)((total + 255) / 256), 256, 0, stream>>>(
            h, edge_src, edge_dst, edge_w, neigh_fb);
        linear_f32_kernel<<<1024, 256, 0, stream>>>(h, neigh_fb, W_self, b_self,
                                                    W_neigh, b_neigh, out);
    }
}

// Round 7
// 141.354 us; speedup vs baseline: 1.0143x; 1.0143x over previous
//
#include <hip/hip_runtime.h>

#define N_NODES 50000
#define N_EDGES 800000
#define D 64

#define NPB 200                      // nodes per bucket (bin key)
#define NB  250                      // buckets (NPB*NB == N_NODES)
#define CAP 4096                     // record capacity per bucket (mean 3200, 15.8 sigma)
#define BT  512                      // threads for bin (8 waves)
#define EPT 8                        // edges per thread in bin (R16 best)
#define CHUNK_E (BT * EPT)           // 4096 edges per block
#define NCHUNKS ((N_EDGES + CHUNK_E - 1) / CHUNK_E)   // 196
#define CONVB 256                    // h->bf16 conversion blocks appended to bin grid

#define CGT 1024                     // csr_gather threads (16 waves) -- R19: was 512
#define NPH 100                      // nodes per half-bucket (csr_gather block)
#define HCAP 2048                    // stage capacity per half (mean 1600, 11 sigma)
#define NTILE ((NPH + 15) / 16)      // 7 MFMA row-tiles per half (last 4 rows masked)

typedef unsigned short ushort_t;
typedef unsigned int   uint_t;
typedef __attribute__((ext_vector_type(8))) short   short8;
typedef __attribute__((ext_vector_type(4))) float   float4v;

// bf16 helpers (RNE down-convert; up-convert is exact)
__device__ __forceinline__ ushort_t f2b(float f) {
    uint_t u = __float_as_uint(f);
    return (ushort_t)((u + 0x7FFFu + ((u >> 16) & 1u)) >> 16);
}
__device__ __forceinline__ float b2f(ushort_t b) {
    return __uint_as_float((uint_t)b << 16);
}
// fp32 bits -> bf16 bits (RNE), kept in the HIGH 16 bits of a uint
__device__ __forceinline__ uint_t rne_hi16(uint_t u) {
    return (u + 0x7FFFu + ((u >> 16) & 1u)) & 0xFFFF0000u;
}
__device__ __forceinline__ float lane_bcast(float v, int l) {
    return __int_as_float(__builtin_amdgcn_readlane(__float_as_int(v), l));
}

// ---------------------------------------------------------------------------
// ws layout (16B-aligned sections):
//   bedges : int2[NB*CAP]     (8.19 MB) bucket-grouped packed records (bin out)
//   h_bf16 : ushort[N*D]      (6.4 MB)
//   cursor : int[NB]          (memset 0; bin rebases to b*CAP + old)
// Binned record: .x=(src<<8)|local_dst, .y=bits(w).
//
// Ground-truth ledger: total ~143 = fill 46.5 (harness poison fill, fixed)
// + bin ~42 + csr_gather + gaps ~2.
//  - R5 (fused, 250 blk x 16 waves): csr_gather 51.5, occ 34% (16 waves/CU).
//  - R6 (500 blk x 8 waves): 57.0, occ STILL 34% -- total waves unchanged
//    (4000); paid +5.5 for duplicated phase A. Occupancy experiment never
//    actually ran.
//  - R19 (this): 500 blk x 16 waves = 8000 waves, 2 blocks/CU -> ~31
//    waves/CU. Single variable vs R5: resident waves 16->31. Discriminates
//    latency-bound (predict ~40-44) vs transaction-wall (stays >=50) for
//    the 42-57 us wall every 800k-edge random pass has hit.
// ---------------------------------------------------------------------------

// ---------------- K1: bin edges by bucket (blocks < NCHUNKS) + h->bf16 (rest) ----
__global__ __launch_bounds__(BT) void bin_h2b_kernel(
    const int* __restrict__ src, const int* __restrict__ dst,
    const float* __restrict__ w, int* __restrict__ cursor,
    int2* __restrict__ bedges,
    const float* __restrict__ h, ushort_t* __restrict__ hb)
{
    if (blockIdx.x >= NCHUNKS) {
        const int nb = gridDim.x - NCHUNKS;
        for (int i = (blockIdx.x - NCHUNKS) * BT + threadIdx.x;
             i < N_NODES * D / 4; i += nb * BT) {
            const float4 v = ((const float4*)h)[i];
            ushort4 o;
            o.x = f2b(v.x); o.y = f2b(v.y); o.z = f2b(v.z); o.w = f2b(v.w);
            ((ushort4*)hb)[i] = o;
        }
        return;
    }

    __shared__ int lh[NB];
    __shared__ int loff[NB];
    __shared__ int lcur[NB];
    __shared__ int gpos[NB];
    __shared__ int part[256];
    __shared__ int2 stage[CHUNK_E];
    __shared__ unsigned char sbk[CHUNK_E];

    const int t = threadIdx.x;
    for (int i = t; i < NB; i += BT) lh[i] = 0;
    __syncthreads();

    const int base = blockIdx.x * CHUNK_E;
    int   my_b[EPT];
    int   my_p[EPT];
    float my_w[EPT];
#pragma unroll
    for (int k = 0; k < EPT; ++k) {
        const int e = base + k * BT + t;
        if (e < N_EDGES) {
            const int d = dst[e];
            const int b = (unsigned)d / NPB;
            my_b[k] = b;
            my_p[k] = (src[e] << 8) | (d - b * NPB);
            my_w[k] = w[e];
            atomicAdd(&lh[b], 1);
        } else {
            my_b[k] = -1;
        }
    }
    __syncthreads();

    const int v = (t < NB) ? lh[t] : 0;
    if (t < 256) part[t] = v;
    __syncthreads();
    for (int off = 1; off < 256; off <<= 1) {
        int p = 0;
        if (t < 256 && t >= off) p = part[t - off];
        __syncthreads();
        if (t < 256) part[t] += p;
        __syncthreads();
    }
    if (t < NB) { loff[t] = part[t] - v; lcur[t] = part[t] - v; }
    __syncthreads();

#pragma unroll
    for (int k = 0; k < EPT; ++k) {
        if (my_b[k] >= 0) {
            const int p = atomicAdd(&lcur[my_b[k]], 1);
            stage[p] = make_int2(my_p[k], __float_as_int(my_w[k]));
            sbk[p] = (unsigned char)my_b[k];
        }
    }
    __syncthreads();

    if (t < NB && lh[t] > 0)
        gpos[t] = t * CAP + atomicAdd(&cursor[t], lh[t]);
    __syncthreads();

    const int tot = min(N_EDGES - base, CHUNK_E);
    for (int s = t; s < tot; s += BT) {
        const int b = sbk[s];
        bedges[gpos[b] + (s - loff[b])] = stage[s];
    }
}

// ---------------- K2: fused half-bucket sort + gather + MFMA linear ----------
// Block = (bucket, half), 16 waves. Phase A: filter + counting sort of my
// 100-node half into LDS. Phase B: 16 waves x 6.25 nodes, 16-deep
// register-accumulate. Phase C: 7x4 MFMA tile tasks.
__global__ __launch_bounds__(CGT) void csr_gather_kernel(
    const int* __restrict__ cursor, const int2* __restrict__ bedges,
    const ushort_t* __restrict__ hb,
    const float* __restrict__ Ws, const float* __restrict__ bs,
    const float* __restrict__ Wn, const float* __restrict__ bn,
    float* __restrict__ out)
{
    __shared__ int      offs[NPH + 1];
    __shared__ int      lcur[NPH];
    __shared__ int      part[128];
    __shared__ __align__(16) uint_t   stage[HCAP];             // 8 KB
    __shared__ __align__(16) ushort_t nstage[NTILE * 16 * D];  // 14 KB

    const int blk = blockIdx.x;
    const int b   = blk >> 1;           // bucket 0..249
    const int lo  = (blk & 1) * NPH;    // local-node base of my half
    const int t   = threadIdx.x;
    const int gb  = b * CAP;
    const int cnt = min(cursor[b], CAP);

    // ---- phase A: histogram of my half ----
    if (t < NPH) lcur[t] = 0;
    __syncthreads();
    for (int e = t; e < cnt; e += CGT) {
        const unsigned ll = (unsigned)((bedges[gb + e].x & 255) - lo);
        if (ll < NPH) atomicAdd(&lcur[ll], 1);
    }
    __syncthreads();

    // exclusive scan of NPH counts (128-thread Hillis-Steele)
    const int v = (t < NPH) ? lcur[t] : 0;
    if (t < 128) part[t] = v;
    __syncthreads();
    for (int off = 1; off < 128; off <<= 1) {
        int p = 0;
        if (t < 128 && t >= off) p = part[t - off];
        __syncthreads();
        if (t < 128) part[t] += p;
        __syncthreads();
    }
    if (t < NPH) {
        const int ex = part[t] - v;
        offs[t] = ex;
        lcur[t] = ex;
    }
    if (t == 0) offs[NPH] = part[127];  // total records in my half
    // zero nstage pad rows (100..111) so tile 7's A-neigh reads are defined
    for (int i = t; i < (NTILE * 16 - NPH) * D; i += CGT) nstage[NPH * D + i] = 0;
    __syncthreads();

    // positioned scatter of my half's records into LDS stage
    for (int e = t; e < cnt; e += CGT) {
        const int2 r = bedges[gb + e];
        const unsigned ll = (unsigned)((r.x & 255) - lo);
        if (ll < NPH) {
            const int p = atomicAdd(&lcur[ll], 1);
            stage[min(p, HCAP - 1)] = (uint_t)(r.x >> 8) | rne_hi16((uint_t)r.y);
        }
    }
    __syncthreads();

    // ---- phase B: per-node gather-accumulate, 16 waves x 6.25 nodes ----
    const int wave = t >> 6;
    const int lane = t & 63;
    const int nbeg = wave * 6 + min(wave, 4);       // waves 0-3: 7 nodes, 4-15: 6
    const int ncnt = 6 + (wave < 4 ? 1 : 0);
    for (int ni = 0; ni < ncnt; ++ni) {
        const int n   = nbeg + ni;
        const int beg = min(offs[n], HCAP);
        const int end = min(offs[n + 1], HCAP);
        float acc = 0.f;
        int e = beg;
        for (; e + 16 <= end; e += 16) {
            uint_t r[16];
            float  vv[16];
#pragma unroll
            for (int k = 0; k < 16; ++k) r[k] = stage[e + k];
#pragma unroll
            for (int k = 0; k < 16; ++k)
                vv[k] = b2f(hb[(size_t)(r[k] & 0xFFFFu) * D + lane]);
#pragma unroll
            for (int k = 0; k < 16; ++k)
                acc = fmaf(__uint_as_float(r[k] & 0xFFFF0000u), vv[k], acc);
        }
        for (; e + 4 <= end; e += 4) {
            uint_t r[4];
            float  vv[4];
#pragma unroll
            for (int k = 0; k < 4; ++k) r[k] = stage[e + k];
#pragma unroll
            for (int k = 0; k < 4; ++k)
                vv[k] = b2f(hb[(size_t)(r[k] & 0xFFFFu) * D + lane]);
#pragma unroll
            for (int k = 0; k < 4; ++k)
                acc = fmaf(__uint_as_float(r[k] & 0xFFFF0000u), vv[k], acc);
        }
        for (; e < end; ++e) {
            const uint_t r = stage[e];
            acc = fmaf(__uint_as_float(r & 0xFFFF0000u),
                       b2f(hb[(size_t)(r & 0xFFFFu) * D + lane]), acc);
        }
        nstage[n * D + lane] = f2b(acc);
    }
    __syncthreads();

    // ---- phase C: MFMA linear, NTILE*4 = 28 tile tasks over 16 waves ----
    const int node0  = b * NPB + lo;    // first output node of my half
    const int row16  = lane & 15;
    const int quad   = lane >> 4;
    for (int task = wave; task < NTILE * 4; task += 16) {
        const int m  = task >> 2;       // row tile 0..6
        const int nt = task & 3;        // col tile 0..3
        const int arow = m * 16 + row16;

        // A-self rows: node0+arow may overrun by <=11 rows for m==6; reads
        // land in later ws sections (in-bounds of allocation) and outputs
        // are store-masked below.
        const size_t abase = (size_t)(node0 + arow) * D + quad * 8;
        const short8 ah0 = *(const short8*)(hb + abase);
        const short8 ah1 = *(const short8*)(hb + abase + 32);
        const ushort_t* sp = nstage + arow * D + quad * 8;
        const short8 an0 = *(const short8*)sp;
        const short8 an1 = *(const short8*)(sp + 32);

        const int col = nt * 16 + row16;
        const float* wsr = Ws + (size_t)col * D + quad * 8;
        const float* wnr = Wn + (size_t)col * D + quad * 8;
        short8 bw[4];   // ws_k0, ws_k1, wn_k0, wn_k1
#pragma unroll
        for (int f = 0; f < 4; ++f) {
            const float* p = (f < 2 ? wsr : wnr) + (f & 1) * 32;
            const float4 w0 = *(const float4*)p;
            const float4 w1 = *(const float4*)(p + 4);
            short8 bwv;
            bwv[0] = (short)f2b(w0.x); bwv[1] = (short)f2b(w0.y);
            bwv[2] = (short)f2b(w0.z); bwv[3] = (short)f2b(w0.w);
            bwv[4] = (short)f2b(w1.x); bwv[5] = (short)f2b(w1.y);
            bwv[6] = (short)f2b(w1.z); bwv[7] = (short)f2b(w1.w);
            bw[f] = bwv;
        }
        float4v acc = {0.f, 0.f, 0.f, 0.f};
        acc = __builtin_amdgcn_mfma_f32_16x16x32_bf16(ah0, bw[0], acc, 0, 0, 0);
        acc = __builtin_amdgcn_mfma_f32_16x16x32_bf16(ah1, bw[1], acc, 0, 0, 0);
        acc = __builtin_amdgcn_mfma_f32_16x16x32_bf16(an0, bw[2], acc, 0, 0, 0);
        acc = __builtin_amdgcn_mfma_f32_16x16x32_bf16(an1, bw[3], acc, 0, 0, 0);

        const float bias = bs[col] + bn[col];
#pragma unroll
        for (int r = 0; r < 4; ++r) {
            const int mr = m * 16 + quad * 4 + r;   // row within my half
            if (mr < NPH)
                out[(size_t)(node0 + mr) * D + col] = fmaxf(acc[r] + bias, 0.f);
        }
    }
}

// ---------------- fallback path (ws too small): fp32 atomic scatter ----------------
__global__ __launch_bounds__(256) void sage_scatter(
    const float* __restrict__ h,
    const int* __restrict__ edge_src,
    const int* __restrict__ edge_dst,
    const float* __restrict__ edge_w,
    float* __restrict__ neigh)
{
    const long long tid = (long long)blockIdx.x * blockDim.x + threadIdx.x;
    const int e = (int)(tid >> 6);
    const int d = (int)(tid & 63);
    if (e >= N_EDGES) return;
    atomicAdd(&neigh[(long long)edge_dst[e] * D + d],
              edge_w[e] * h[(long long)edge_src[e] * D + d]);
}

__global__ __launch_bounds__(256, 2) void linear_f32_kernel(
    const float* __restrict__ h, const float* __restrict__ neigh,
    const float* __restrict__ Ws, const float* __restrict__ bs,
    const float* __restrict__ Wn, const float* __restrict__ bn,
    float* __restrict__ out)
{
    const int lane   = threadIdx.x & 63;
    const int gwave  = (blockIdx.x * blockDim.x + threadIdx.x) >> 6;
    const int nwaves = (gridDim.x * blockDim.x) >> 6;

    float Wsr[D], Wnr[D];
#pragma unroll
    for (int k = 0; k < D; k += 4) {
        const float4 a = *(const float4*)&Ws[(size_t)lane * D + k];
        const float4 b = *(const float4*)&Wn[(size_t)lane * D + k];
        Wsr[k] = a.x; Wsr[k+1] = a.y; Wsr[k+2] = a.z; Wsr[k+3] = a.w;
        Wnr[k] = b.x; Wnr[k+1] = b.y; Wnr[k+2] = b.z; Wnr[k+3] = b.w;
    }
    const float bias = bs[lane] + bn[lane];

    for (int n = gwave; n < N_NODES; n += nwaves) {
        const float hv = h[(size_t)n * D + lane];
        const float nv = neigh[(size_t)n * D + lane];
        float o = bias;
#pragma unroll
        for (int k = 0; k < D; ++k) {
            o = fmaf(lane_bcast(hv, k), Wsr[k], o);
            o = fmaf(lane_bcast(nv, k), Wnr[k], o);
        }
        out[(size_t)n * D + lane] = fmaxf(o, 0.f);
    }
}

extern "C" void kernel_launch(void* const* d_in, const int* in_sizes, int n_in,
                              void* d_out, int out_size, void* d_ws, size_t ws_size,
                              hipStream_t stream)
{
    const float* h        = (const float*)d_in[0];
    const int*   edge_src = (const int*)d_in[1];
    const int*   edge_dst = (const int*)d_in[2];
    const float* edge_w   = (const float*)d_in[3];
    const float* W_self   = (const float*)d_in[4];
    const float* b_self   = (const float*)d_in[5];
    const float* W_neigh  = (const float*)d_in[6];
    const float* b_neigh  = (const float*)d_in[7];
    float*       out      = (float*)d_out;

    // ws layout
    int2*     bedges = (int2*)d_ws;                               // NB*CAP int2
    ushort_t* hb     = (ushort_t*)(bedges + (size_t)NB * CAP);    // N*D ushort
    int*      cursor = (int*)(hb + (size_t)N_NODES * D);          // NB
    const size_t needed = (size_t)NB * CAP * 8 + (size_t)N_NODES * D * 2 + NB * 4;

    if (ws_size >= needed) {
        hipMemsetAsync(cursor, 0, NB * sizeof(int), stream);
        bin_h2b_kernel<<<NCHUNKS + CONVB, BT, 0, stream>>>(
            edge_src, edge_dst, edge_w, cursor, bedges, h, hb);
        csr_gather_kernel<<<NB * 2, CGT, 0, stream>>>(
            cursor, bedges, hb, W_self, b_self, W_neigh, b_neigh, out);
    } else {
        float* neigh_fb = (float*)d_ws;
        hipMemsetAsync(neigh_fb, 0, (size_t)N_NODES * D * sizeof(float), stream);
        const long long total = (long long)N_EDGES * 64;
        sage_scatter<<<(int)((total + 255) / 256), 256, 0, stream>>>(
            h, edge_src, edge_dst, edge_w, neigh_fb);
        linear_f32_kernel<<<1024, 256, 0, stream>>>(h, neigh_fb, W_self, b_self,
                                                    W_neigh, b_neigh, out);
    }
}